// Round 1
// baseline (233.596 us; speedup 1.0000x reference)
//
#include <hip/hip_runtime.h>

// Problem constants (mirror the reference)
constexpr int N_A   = 3550;
constexpr int N_D   = 20000;
constexpr int DUMMY = 120000;
constexpr int LW    = 20;      // walk_length
constexpr int CC    = 7;       // context_size
constexpr int WPN   = 100;
constexpr int BB    = 2048;    // batch
constexpr int W     = BB * WPN;        // 204800 walks
constexpr int NUM_WIN = 1 + LW + 1 - CC; // 15
constexpr int SEC   = NUM_WIN * W * CC;  // 21,504,000 ints per output
constexpr int BLK   = 256;
constexpr int BLOCKS_PER_SEC = W / BLK;  // 800

// One block handles 256 walks: phase 1 computes the 21-element mapped walk
// into LDS; phase 2 writes the 15 context windows as fully-coalesced int4
// stores (each window's 256 rows x 7 ints = 1792 contiguous ints).
__global__ __launch_bounds__(BLK) void walk_kernel(
    const float* __restrict__ pos_rand,
    const float* __restrict__ neg_rand,
    const int*   __restrict__ batch,
    const int*   __restrict__ rowptr_ad,
    const int*   __restrict__ col_ad,
    const int*   __restrict__ rowptr_da,
    const int*   __restrict__ col_da,
    int nnz_ad, int nnz_da,
    int* __restrict__ out)
{
    __shared__ int s_rw[BLK * (LW + 1)];   // 256*21*4 = 21504 B

    const bool is_neg = blockIdx.x >= BLOCKS_PER_SEC;
    const int  blk    = is_neg ? (int)blockIdx.x - BLOCKS_PER_SEC : (int)blockIdx.x;
    const int  w0     = blk * BLK;
    const int  w      = w0 + (int)threadIdx.x;

    // Load this walk's 20 uniforms with float4 loads (80 B contiguous).
    float u[LW];
    {
        const float4* r4 = (const float4*)((is_neg ? neg_rand : pos_rand) + (size_t)w * LW);
        #pragma unroll
        for (int q = 0; q < 5; ++q) {
            float4 v = r4[q];
            u[q * 4 + 0] = v.x; u[q * 4 + 1] = v.y;
            u[q * 4 + 2] = v.z; u[q * 4 + 3] = v.w;
        }
    }

    int cur = batch[w & (BB - 1)];        // tile(batch, WPN): w % 2048
    int* my = &s_rw[threadIdx.x * (LW + 1)];
    my[0] = cur;                          // position 0: a-type, < 3550, unmapped

    if (!is_neg) {
        #pragma unroll
        for (int i = 0; i < LW; ++i) {
            const int* rp  = (i & 1) ? rowptr_da : rowptr_ad;
            const int* cl  = (i & 1) ? col_da   : col_ad;
            const int  nnz = (i & 1) ? nnz_da   : nnz_ad;
            int nxt = DUMMY;
            if (cur != DUMMY) {
                int r0 = rp[cur];
                int rc = rp[cur + 1] - r0;
                if (rc > 0) {
                    // exact float32 replica of (u * float(rowcount)).astype(int32)
                    int idx = (int)(u[i] * (float)rc) + r0;
                    idx = min(max(idx, 0), nnz - 1);
                    nxt = cl[idx];
                }
            }
            cur = nxt;
            const int j = i + 1;
            // rw = cur + OFFSET[j]; clamp >DUMMY -> DUMMY; remap >=3550 -> +5550.
            // Net: DUMMY stays DUMMY; odd j: cur+3550+5550 = cur+9100; even j: cur.
            my[j] = (cur == DUMMY) ? DUMMY : ((j & 1) ? cur + 9100 : cur);
        }
    } else {
        #pragma unroll
        for (int i = 0; i < LW; ++i) {
            const int j = i + 1;
            // i even -> n=N_D, lands on odd j (d-type): +3550 offset +5550 remap
            // i odd  -> n=N_A, lands on even j (a-type): unchanged
            my[j] = (j & 1) ? (int)(u[i] * 20000.0f) + 9100
                            : (int)(u[i] * 3550.0f);
        }
    }

    __syncthreads();

    // Phase 2: window writes. Window j, rows [j*W + w0, j*W + w0 + 256):
    // contiguous run of 1792 ints = 448 int4 (16B-aligned since w0 % 256 == 0).
    int* outSec = out + (is_neg ? SEC : 0);
    #pragma unroll 1
    for (int j = 0; j < NUM_WIN; ++j) {
        const int base = (j * W + w0) * CC;      // max ~21.5M, fits int32
        int4* ob = (int4*)(outSec + base);
        for (int t4 = threadIdx.x; t4 < (BLK * CC) / 4; t4 += BLK) {
            const int e = t4 * 4;
            int4 v;
            v.x = s_rw[((e + 0) / 7) * (LW + 1) + j + (e + 0) % 7];
            v.y = s_rw[((e + 1) / 7) * (LW + 1) + j + (e + 1) % 7];
            v.z = s_rw[((e + 2) / 7) * (LW + 1) + j + (e + 2) % 7];
            v.w = s_rw[((e + 3) / 7) * (LW + 1) + j + (e + 3) % 7];
            ob[t4] = v;
        }
    }
}

extern "C" void kernel_launch(void* const* d_in, const int* in_sizes, int n_in,
                              void* d_out, int out_size, void* d_ws, size_t ws_size,
                              hipStream_t stream) {
    const float* pos_rand  = (const float*)d_in[0];
    const float* neg_rand  = (const float*)d_in[1];
    const int*   batch     = (const int*)d_in[2];
    const int*   rowptr_ad = (const int*)d_in[3];
    const int*   col_ad    = (const int*)d_in[4];
    const int*   rowptr_da = (const int*)d_in[5];
    const int*   col_da    = (const int*)d_in[6];
    const int nnz_ad = in_sizes[4];
    const int nnz_da = in_sizes[6];

    walk_kernel<<<2 * BLOCKS_PER_SEC, BLK, 0, stream>>>(
        pos_rand, neg_rand, batch,
        rowptr_ad, col_ad, rowptr_da, col_da,
        nnz_ad, nnz_da, (int*)d_out);
}